// Round 5
// baseline (779.994 us; speedup 1.0000x reference)
//
#include <hip/hip_runtime.h>
#include <hip/hip_bf16.h>
#include <stdint.h>

#define BATCH 16
#define SEQ   2048
#define DK    64
#define BQ    (BATCH * SEQ)

typedef float  f32x4  __attribute__((ext_vector_type(4)));
typedef __bf16 bf16x8 __attribute__((ext_vector_type(8)));
typedef unsigned short u16x8 __attribute__((ext_vector_type(8)));
typedef unsigned short u16x4 __attribute__((ext_vector_type(4)));

#define MFMA16(a, b, c) __builtin_amdgcn_mfma_f32_16x16x32_bf16((a), (b), (c), 0, 0, 0)

__device__ __forceinline__ unsigned short bfbits(float f) {
  return __builtin_bit_cast(unsigned short, __float2bfloat16(f));
}

__device__ __forceinline__ bf16x8 fragld(const float* p) {
  f32x4 a = *(const f32x4*)p;
  f32x4 c = *(const f32x4*)(p + 4);
  bf16x8 r;
  r[0] = (__bf16)a[0]; r[1] = (__bf16)a[1]; r[2] = (__bf16)a[2]; r[3] = (__bf16)a[3];
  r[4] = (__bf16)c[0]; r[5] = (__bf16)c[1]; r[6] = (__bf16)c[2]; r[7] = (__bf16)c[3];
  return r;
}

__device__ __forceinline__ void cvt_store(unsigned short* dst, f32x4 a, f32x4 c) {
  u16x8 v;
  v[0] = bfbits(a[0]); v[1] = bfbits(a[1]); v[2] = bfbits(a[2]); v[3] = bfbits(a[3]);
  v[4] = bfbits(c[0]); v[5] = bfbits(c[1]); v[6] = bfbits(c[2]); v[7] = bfbits(c[3]);
  *(u16x8*)dst = v;
}

// ---------------- Kernel A: inverted row sums -> ws ----------------
// One block = 64 q-rows of one batch-head, 4 waves, full key sweep.
// LDS 16KB (K only) -> target 8 blocks/CU for max TLP. No max-subtraction
// needed: |S|/8 <~ 6 fits f32 exp comfortably.
__global__ __launch_bounds__(256, 8)
void ck_sums(const float* __restrict__ qr, const float* __restrict__ kr,
             const float* __restrict__ qp, const float* __restrict__ kp,
             float* __restrict__ wsums)
{
  __shared__ __align__(16) unsigned short Kr[64][64];
  __shared__ __align__(16) unsigned short Kp[64][64];

  const int tid  = threadIdx.x;
  const int wq   = tid >> 6, lane = tid & 63;
  const int lrow = lane & 15, lgrp = lane >> 4;

  // XCD-affinity swizzle: 64 consecutive logical blocks (2 batch-heads) per XCD.
  const int hw = blockIdx.x;
  const int logical = (hw & 7) * 64 + (hw >> 3);
  const int b = logical >> 5, qtile = logical & 31;

  const size_t bo = (size_t)b * SEQ * DK;
  const float* qrb = qr + bo; const float* qpb = qp + bo;
  const float* krb = kr + bo; const float* kpb = kp + bo;

  const int qrow = qtile * 64 + wq * 16 + lrow;
  bf16x8 aQ0, aQ1, aQ2, aQ3;
  {
    const float* pr0 = qrb + (size_t)qrow * DK + lgrp * 8;
    const float* pp0 = qpb + (size_t)qrow * DK + lgrp * 8;
    aQ0 = fragld(pr0);       // q_r d[0:32)
    aQ1 = fragld(pr0 + 32);  // q_r d[32:64)
    aQ2 = fragld(pp0);       // q_p d[0:32)
    aQ3 = fragld(pp0 + 32);  // q_p d[32:64)
  }

  const int skK = tid >> 2, sdp = tid & 3;
  float lsR[4] = {0.f, 0.f, 0.f, 0.f};
  float lsP[4] = {0.f, 0.f, 0.f, 0.f};

  for (int i = 0; i < 32; ++i) {
    const int k0 = i * 64;
    __syncthreads();
    { // stage K tile (coalesced; sequenced r-then-p to limit register liveness)
      const int c0 = sdp * 2, c1 = sdp * 2 + 1, sw = skK & 7;
      const float* gr = krb + (size_t)(k0 + skK) * DK + sdp * 16;
      f32x4 r0 = ((const f32x4*)gr)[0], r1 = ((const f32x4*)gr)[1];
      f32x4 r2 = ((const f32x4*)gr)[2], r3 = ((const f32x4*)gr)[3];
      cvt_store(&Kr[skK][(c0 ^ sw) * 8], r0, r1);
      cvt_store(&Kr[skK][(c1 ^ sw) * 8], r2, r3);
      const float* gp = kpb + (size_t)(k0 + skK) * DK + sdp * 16;
      f32x4 p0 = ((const f32x4*)gp)[0], p1 = ((const f32x4*)gp)[1];
      f32x4 p2 = ((const f32x4*)gp)[2], p3 = ((const f32x4*)gp)[3];
      cvt_store(&Kp[skK][(c0 ^ sw) * 8], p0, p1);
      cvt_store(&Kp[skK][(c1 ^ sw) * 8], p2, p3);
    }
    __syncthreads();
    #pragma unroll
    for (int t = 0; t < 4; ++t) {
      const int key16 = t * 16 + lrow;
      const int swk = lrow & 7;
      bf16x8 b0 = __builtin_bit_cast(bf16x8, *(const u16x8*)&Kr[key16][((lgrp    ) ^ swk) * 8]);
      bf16x8 b1 = __builtin_bit_cast(bf16x8, *(const u16x8*)&Kr[key16][((lgrp + 4) ^ swk) * 8]);
      bf16x8 b2 = __builtin_bit_cast(bf16x8, *(const u16x8*)&Kp[key16][((lgrp    ) ^ swk) * 8]);
      bf16x8 b3 = __builtin_bit_cast(bf16x8, *(const u16x8*)&Kp[key16][((lgrp + 4) ^ swk) * 8]);
      f32x4 t1 = {}, t2 = {}, sp = {};
      t1 = MFMA16(aQ0, b0, t1); t1 = MFMA16(aQ1, b1, t1);  // q_r.k_r
      t2 = MFMA16(aQ2, b2, t2); t2 = MFMA16(aQ3, b3, t2);  // q_p.k_p
      sp = MFMA16(aQ0, b2, sp); sp = MFMA16(aQ1, b3, sp);  // q_r.k_p
      sp = MFMA16(aQ2, b0, sp); sp = MFMA16(aQ3, b1, sp);  // q_p.k_r
      #pragma unroll
      for (int r = 0; r < 4; ++r) {
        lsR[r] += __expf((t1[r] - t2[r]) * 0.125f);
        lsP[r] += __expf(sp[r] * 0.125f);
      }
    }
  }

  #pragma unroll
  for (int r = 0; r < 4; ++r) {
    float sR = lsR[r], sP = lsP[r];
    #pragma unroll
    for (int m = 1; m < 16; m <<= 1) {
      sR += __shfl_xor(sR, m, 64);
      sP += __shfl_xor(sP, m, 64);
    }
    if (lrow == 0) {
      const size_t row = (size_t)b * SEQ + qtile * 64 + wq * 16 + lgrp * 4 + r;
      wsums[row]      = 1.0f / sR;
      wsums[BQ + row] = 1.0f / sP;
    }
  }
}

// ---------------- Kernel B: PV + normalized attn ----------------
// One block = 64 q-rows x full key range, 4 waves, LDS 40KB -> 4 blocks/CU.
// K AND V register-prefetched across compute (T14). attn written from bf16 P
// panels as FULL 128B lines per store instruction (8 lanes x 16B per row), NT.
// PV uses sign-flipped (-Pp) fragments: one accumulator set per output.
__global__ __launch_bounds__(256, 4)
void ck_attn2(const float* __restrict__ qr, const float* __restrict__ kr,
              const float* __restrict__ vr, const float* __restrict__ qp,
              const float* __restrict__ kp, const float* __restrict__ vp,
              const float* __restrict__ wsums, float* __restrict__ dout)
{
  __shared__ __align__(16) unsigned short Kr[64][64];
  __shared__ __align__(16) unsigned short Kp[64][64];
  __shared__ __align__(16) unsigned short Vr[64][64];
  __shared__ __align__(16) unsigned short Vp[64][64];
  __shared__ __align__(16) unsigned short Pr[64][32];
  __shared__ __align__(16) unsigned short Pp[64][32];

  const int tid  = threadIdx.x;
  const int wq   = tid >> 6, lane = tid & 63;
  const int lrow = lane & 15, lgrp = lane >> 4;

  const int hw = blockIdx.x;
  const int logical = (hw & 7) * 64 + (hw >> 3);
  const int b = logical >> 5, qtile = logical & 31;

  const size_t bo = (size_t)b * SEQ * DK;
  const float* qrb = qr + bo; const float* qpb = qp + bo;
  const float* krb = kr + bo; const float* kpb = kp + bo;
  const float* vrb = vr + bo; const float* vpb = vp + bo;

  float* outR = dout;
  float* outP = dout + (size_t)BQ * DK;
  float* attn = dout + (size_t)2 * BQ * DK + ((size_t)b * SEQ + (size_t)qtile * 64) * SEQ;

  const int qrow = qtile * 64 + wq * 16 + lrow;
  bf16x8 aQ0, aQ1, aQ2, aQ3;
  {
    const float* pr0 = qrb + (size_t)qrow * DK + lgrp * 8;
    const float* pp0 = qpb + (size_t)qrow * DK + lgrp * 8;
    aQ0 = fragld(pr0);
    aQ1 = fragld(pr0 + 32);
    aQ2 = fragld(pp0);
    aQ3 = fragld(pp0 + 32);
  }

  const int skK = tid >> 2, sdp = tid & 3;        // K staging
  const int skV = tid & 15, sdV = (tid >> 4) * 4; // V staging
  const int qloc = wq * 16 + lgrp * 4;

  // normalizers from kernel A (already inverted)
  float iR[4], iP[4];
  {
    const size_t base = (size_t)b * SEQ + qtile * 64 + qloc;
    #pragma unroll
    for (int r = 0; r < 4; ++r) {
      iR[r] = wsums[base + r];
      iP[r] = wsums[BQ + base + r];
    }
  }

  // prefetch registers (live across compute phases)
  f32x4 kA0, kA1, kA2, kA3, kB0, kB1, kB2, kB3;
  f32x4 va0, va1, va2, va3, vc0, vc1, vc2, vc3;
  auto loadK = [&](int k0) {
    const float* gr = krb + (size_t)(k0 + skK) * DK + sdp * 16;
    const float* gp = kpb + (size_t)(k0 + skK) * DK + sdp * 16;
    kA0 = ((const f32x4*)gr)[0]; kA1 = ((const f32x4*)gr)[1];
    kA2 = ((const f32x4*)gr)[2]; kA3 = ((const f32x4*)gr)[3];
    kB0 = ((const f32x4*)gp)[0]; kB1 = ((const f32x4*)gp)[1];
    kB2 = ((const f32x4*)gp)[2]; kB3 = ((const f32x4*)gp)[3];
  };
  auto loadV = [&](int k0) {
    const float* v0  = vrb + (size_t)(k0 + skV) * DK + sdV;
    const float* c0p = vpb + (size_t)(k0 + skV) * DK + sdV;
    va0 = *(const f32x4*)(v0);
    va1 = *(const f32x4*)(v0 + 16 * DK);
    va2 = *(const f32x4*)(v0 + 32 * DK);
    va3 = *(const f32x4*)(v0 + 48 * DK);
    vc0 = *(const f32x4*)(c0p);
    vc1 = *(const f32x4*)(c0p + 16 * DK);
    vc2 = *(const f32x4*)(c0p + 32 * DK);
    vc3 = *(const f32x4*)(c0p + 48 * DK);
  };
  auto storeK = [&]() {
    const int c0 = sdp * 2, c1 = sdp * 2 + 1, sw = skK & 7;
    cvt_store(&Kr[skK][(c0 ^ sw) * 8], kA0, kA1);
    cvt_store(&Kr[skK][(c1 ^ sw) * 8], kA2, kA3);
    cvt_store(&Kp[skK][(c0 ^ sw) * 8], kB0, kB1);
    cvt_store(&Kp[skK][(c1 ^ sw) * 8], kB2, kB3);
  };
  auto storeV = [&]() {
    #pragma unroll
    for (int pass = 0; pass < 4; ++pass) {
      const f32x4 a = pass == 0 ? va0 : pass == 1 ? va1 : pass == 2 ? va2 : va3;
      const f32x4 c = pass == 0 ? vc0 : pass == 1 ? vc1 : pass == 2 ? vc2 : vc3;
      const int key = pass * 16 + skV;
      const int kc = key >> 3, kl = key & 7;
      #pragma unroll
      for (int j = 0; j < 4; ++j) {
        const int d = sdV + j;
        Vr[d][(kc ^ (d & 7)) * 8 + kl] = bfbits(a[j]);
        Vp[d][(kc ^ (d & 7)) * 8 + kl] = bfbits(c[j]);
      }
    }
  };

  const u16x8 SGN = {0x8000, 0x8000, 0x8000, 0x8000, 0x8000, 0x8000, 0x8000, 0x8000};
  f32x4 accR[4] = {}, accP[4] = {};

  loadK(0); loadV(0);
  for (int i = 0; i < 32; ++i) {
    const int k0 = i * 64;
    __syncthreads();            // previous compute done with LDS
    storeK();
    storeV();
    __syncthreads();            // staged tile visible
    if (i < 31) { loadK(k0 + 64); loadV(k0 + 64); }  // T14: hidden by compute

    #pragma unroll
    for (int h = 0; h < 2; ++h) {
      #pragma unroll
      for (int t = 0; t < 2; ++t) {
        const int key16 = (h * 2 + t) * 16 + lrow;
        const int swk = lrow & 7;
        bf16x8 b0 = __builtin_bit_cast(bf16x8, *(const u16x8*)&Kr[key16][((lgrp    ) ^ swk) * 8]);
        bf16x8 b1 = __builtin_bit_cast(bf16x8, *(const u16x8*)&Kr[key16][((lgrp + 4) ^ swk) * 8]);
        bf16x8 b2 = __builtin_bit_cast(bf16x8, *(const u16x8*)&Kp[key16][((lgrp    ) ^ swk) * 8]);
        bf16x8 b3 = __builtin_bit_cast(bf16x8, *(const u16x8*)&Kp[key16][((lgrp + 4) ^ swk) * 8]);
        f32x4 t1 = {}, t2 = {}, sp = {};
        t1 = MFMA16(aQ0, b0, t1); t1 = MFMA16(aQ1, b1, t1);
        t2 = MFMA16(aQ2, b2, t2); t2 = MFMA16(aQ3, b3, t2);
        sp = MFMA16(aQ0, b2, sp); sp = MFMA16(aQ1, b3, sp);
        sp = MFMA16(aQ2, b0, sp); sp = MFMA16(aQ3, b1, sp);
        #pragma unroll
        for (int r = 0; r < 4; ++r) {
          const float er = __expf((t1[r] - t2[r]) * 0.125f) * iR[r];
          const float ep = __expf(sp[r] * 0.125f) * iP[r];
          const int row = qloc + r, col = t * 16 + lrow;
          const int pc = ((col >> 3) ^ (row & 3)) * 8 + (col & 7);
          Pr[row][pc] = bfbits(er);   // wave-private rows: no barrier
          Pp[row][pc] = bfbits(ep);
        }
      }
      { // PV: accR += Pr.Vr + (-Pp).Vp ; accP += Pr.Vp + Pp.Vr
        const int prow = wq * 16 + lrow;
        u16x8 uar = *(const u16x8*)&Pr[prow][(lgrp ^ (prow & 3)) * 8];
        u16x8 uap = *(const u16x8*)&Pp[prow][(lgrp ^ (prow & 3)) * 8];
        u16x8 uan = uap ^ SGN;
        bf16x8 apr = __builtin_bit_cast(bf16x8, uar);
        bf16x8 app = __builtin_bit_cast(bf16x8, uap);
        bf16x8 apn = __builtin_bit_cast(bf16x8, uan);
        #pragma unroll
        for (int nt = 0; nt < 4; ++nt) {
          const int d = nt * 16 + lrow;
          const int cv = ((h * 4 + lgrp) ^ (d & 7)) * 8;
          bf16x8 bvr = __builtin_bit_cast(bf16x8, *(const u16x8*)&Vr[d][cv]);
          bf16x8 bvp = __builtin_bit_cast(bf16x8, *(const u16x8*)&Vp[d][cv]);
          accR[nt] = MFMA16(apr, bvr, accR[nt]);
          accR[nt] = MFMA16(apn, bvp, accR[nt]);
          accP[nt] = MFMA16(apr, bvp, accP[nt]);
          accP[nt] = MFMA16(app, bvr, accP[nt]);
        }
      }
      { // attn write: FULL 128B lines per instruction (8 lanes x 16B per row)
        const int j8 = lane & 7;
        #pragma unroll
        for (int s = 0; s < 2; ++s) {
          const int arow = wq * 16 + s * 8 + (lane >> 3);
          const int pc = (((j8 >> 1) ^ (arow & 3)) * 8) + (j8 & 1) * 4;
          u16x4 ua = *(const u16x4*)&Pr[arow][pc];
          f32x4 fa;
          #pragma unroll
          for (int q = 0; q < 4; ++q)
            fa[q] = __builtin_bit_cast(float, (unsigned)ua[q] << 16);
          float* dst = attn + (size_t)arow * SEQ + k0 + h * 32 + j8 * 4;
          __builtin_nontemporal_store(fa, (f32x4*)dst);
        }
      }
    }
  }

  // ---- O writes (through L2; small stream, avoids partial-line NT RMW) ----
  #pragma unroll
  for (int nt = 0; nt < 4; ++nt) {
    const int d = nt * 16 + lrow;
    #pragma unroll
    for (int r = 0; r < 4; ++r) {
      const size_t o = ((size_t)b * SEQ + qtile * 64 + qloc + r) * DK + d;
      outR[o] = accR[nt][r];
      outP[o] = accP[nt][r];
    }
  }
}

extern "C" void kernel_launch(void* const* d_in, const int* in_sizes, int n_in,
                              void* d_out, int out_size, void* d_ws, size_t ws_size,
                              hipStream_t stream)
{
  const float* qr = (const float*)d_in[0];
  const float* kr = (const float*)d_in[1];
  const float* vr = (const float*)d_in[2];
  const float* qp = (const float*)d_in[3];
  const float* kp = (const float*)d_in[4];
  const float* vp = (const float*)d_in[5];
  float* out = (float*)d_out;
  float* wsums = (float*)d_ws;   // 2*BQ floats = 256KB

  ck_sums<<<SEQ / 64 * BATCH, 256, 0, stream>>>(qr, kr, qp, kp, wsums);
  ck_attn2<<<SEQ / 64 * BATCH, 256, 0, stream>>>(qr, kr, vr, qp, kp, vp, wsums, out);
}

// Round 6
// 479.963 us; speedup vs baseline: 1.6251x; 1.6251x over previous
//
#include <hip/hip_runtime.h>
#include <hip/hip_bf16.h>
#include <stdint.h>

#define BATCH 16
#define SEQ   2048
#define DK    64
#define BQ    (BATCH * SEQ)

typedef float  f32x4  __attribute__((ext_vector_type(4)));
typedef __bf16 bf16x8 __attribute__((ext_vector_type(8)));
typedef unsigned short u16x8 __attribute__((ext_vector_type(8)));
typedef unsigned short u16x4 __attribute__((ext_vector_type(4)));

#define MFMA16(a, b, c) __builtin_amdgcn_mfma_f32_16x16x32_bf16((a), (b), (c), 0, 0, 0)

__device__ __forceinline__ unsigned short bfbits(float f) {
  return __builtin_bit_cast(unsigned short, __float2bfloat16(f));
}

__device__ __forceinline__ bf16x8 fragld(const float* p) {
  f32x4 a = *(const f32x4*)p;
  f32x4 c = *(const f32x4*)(p + 4);
  bf16x8 r;
  r[0] = (__bf16)a[0]; r[1] = (__bf16)a[1]; r[2] = (__bf16)a[2]; r[3] = (__bf16)a[3];
  r[4] = (__bf16)c[0]; r[5] = (__bf16)c[1]; r[6] = (__bf16)c[2]; r[7] = (__bf16)c[3];
  return r;
}

__device__ __forceinline__ void cvt_store(unsigned short* dst, f32x4 a, f32x4 c) {
  u16x8 v;
  v[0] = bfbits(a[0]); v[1] = bfbits(a[1]); v[2] = bfbits(a[2]); v[3] = bfbits(a[3]);
  v[4] = bfbits(c[0]); v[5] = bfbits(c[1]); v[6] = bfbits(c[2]); v[7] = bfbits(c[3]);
  *(u16x8*)dst = v;
}

// ---------------- Kernel A: partial row sums -> ws ----------------
// One block = 64 q-rows x one 512-key slice. 2048 blocks -> 8 blocks/CU,
// 32 waves/CU: TLP hides cold-HBM K loads (no register prefetch; keeps VGPR
// under 64 for full occupancy). No max-subtraction: |S|/8 <~ 6 fits f32 exp.
__global__ __launch_bounds__(256, 8)
void ck_sums(const float* __restrict__ qr, const float* __restrict__ kr,
             const float* __restrict__ qp, const float* __restrict__ kp,
             float* __restrict__ wsums)
{
  __shared__ __align__(16) unsigned short Kr[64][64];
  __shared__ __align__(16) unsigned short Kp[64][64];

  const int tid  = threadIdx.x;
  const int wq   = tid >> 6, lane = tid & 63;
  const int lrow = lane & 15, lgrp = lane >> 4;

  // XCD swizzle: 256 consecutive logical blocks (2 batch-heads) per XCD.
  const int hw = blockIdx.x;
  const int logical = (hw & 7) * 256 + (hw >> 3);
  const int b = logical >> 7, qtile = (logical >> 2) & 31, slice = logical & 3;

  const size_t bo = (size_t)b * SEQ * DK;
  const float* qrb = qr + bo; const float* qpb = qp + bo;
  const float* krb = kr + bo; const float* kpb = kp + bo;

  const int qrow = qtile * 64 + wq * 16 + lrow;
  bf16x8 aQ0, aQ1, aQ2, aQ3;
  {
    const float* pr0 = qrb + (size_t)qrow * DK + lgrp * 8;
    const float* pp0 = qpb + (size_t)qrow * DK + lgrp * 8;
    aQ0 = fragld(pr0);       // q_r d[0:32)
    aQ1 = fragld(pr0 + 32);  // q_r d[32:64)
    aQ2 = fragld(pp0);       // q_p d[0:32)
    aQ3 = fragld(pp0 + 32);  // q_p d[32:64)
  }

  const int skK = tid >> 2, sdp = tid & 3;
  const int kbase = slice * 512;
  float lsR[4] = {0.f, 0.f, 0.f, 0.f};
  float lsP[4] = {0.f, 0.f, 0.f, 0.f};

  for (int i = 0; i < 8; ++i) {
    const int k0 = kbase + i * 64;
    __syncthreads();
    { // stage K tile (coalesced)
      const int c0 = sdp * 2, c1 = sdp * 2 + 1, sw = skK & 7;
      const float* gr = krb + (size_t)(k0 + skK) * DK + sdp * 16;
      f32x4 r0 = ((const f32x4*)gr)[0], r1 = ((const f32x4*)gr)[1];
      f32x4 r2 = ((const f32x4*)gr)[2], r3 = ((const f32x4*)gr)[3];
      const float* gp = kpb + (size_t)(k0 + skK) * DK + sdp * 16;
      f32x4 p0 = ((const f32x4*)gp)[0], p1 = ((const f32x4*)gp)[1];
      f32x4 p2 = ((const f32x4*)gp)[2], p3 = ((const f32x4*)gp)[3];
      cvt_store(&Kr[skK][(c0 ^ sw) * 8], r0, r1);
      cvt_store(&Kr[skK][(c1 ^ sw) * 8], r2, r3);
      cvt_store(&Kp[skK][(c0 ^ sw) * 8], p0, p1);
      cvt_store(&Kp[skK][(c1 ^ sw) * 8], p2, p3);
    }
    __syncthreads();
    #pragma unroll
    for (int t = 0; t < 4; ++t) {
      const int key16 = t * 16 + lrow;
      const int swk = lrow & 7;
      bf16x8 b0 = __builtin_bit_cast(bf16x8, *(const u16x8*)&Kr[key16][((lgrp    ) ^ swk) * 8]);
      bf16x8 b1 = __builtin_bit_cast(bf16x8, *(const u16x8*)&Kr[key16][((lgrp + 4) ^ swk) * 8]);
      bf16x8 b2 = __builtin_bit_cast(bf16x8, *(const u16x8*)&Kp[key16][((lgrp    ) ^ swk) * 8]);
      bf16x8 b3 = __builtin_bit_cast(bf16x8, *(const u16x8*)&Kp[key16][((lgrp + 4) ^ swk) * 8]);
      f32x4 t1 = {}, t2 = {}, sp = {};
      t1 = MFMA16(aQ0, b0, t1); t1 = MFMA16(aQ1, b1, t1);  // q_r.k_r
      t2 = MFMA16(aQ2, b2, t2); t2 = MFMA16(aQ3, b3, t2);  // q_p.k_p
      sp = MFMA16(aQ0, b2, sp); sp = MFMA16(aQ1, b3, sp);  // q_r.k_p
      sp = MFMA16(aQ2, b0, sp); sp = MFMA16(aQ3, b1, sp);  // q_p.k_r
      #pragma unroll
      for (int r = 0; r < 4; ++r) {
        lsR[r] += __expf((t1[r] - t2[r]) * 0.125f);
        lsP[r] += __expf(sp[r] * 0.125f);
      }
    }
  }

  #pragma unroll
  for (int r = 0; r < 4; ++r) {
    float sR = lsR[r], sP = lsP[r];
    #pragma unroll
    for (int m = 1; m < 16; m <<= 1) {
      sR += __shfl_xor(sR, m, 64);
      sP += __shfl_xor(sP, m, 64);
    }
    if (lrow == 0) {
      const size_t row = (size_t)b * SEQ + qtile * 64 + wq * 16 + lgrp * 4 + r;
      wsums[(size_t)(slice * 2 + 0) * BQ + row] = sR;   // partial, not inverted
      wsums[(size_t)(slice * 2 + 1) * BQ + row] = sP;
    }
  }
}

// ---------------- Kernel B: PV + normalized attn (one sweep) ----------------
// One block = 64 q-rows x one 1024-key half. 1024 blocks -> 4 blocks/CU
// (LDS 40KB), 16 waves/CU. V register-prefetched across compute (V is
// HBM-cold); K loaded in staging phase (L2-warm from ck_sums, same XCD).
// attn written once, normalized, FULL 128B lines, NT. O via atomicAdd
// (2 commutative contributions -> deterministic).
__global__ __launch_bounds__(256, 4)
void ck_main(const float* __restrict__ qr, const float* __restrict__ kr,
             const float* __restrict__ vr, const float* __restrict__ qp,
             const float* __restrict__ kp, const float* __restrict__ vp,
             const float* __restrict__ wsums, float* __restrict__ dout)
{
  __shared__ __align__(16) unsigned short Kr[64][64];
  __shared__ __align__(16) unsigned short Kp[64][64];
  __shared__ __align__(16) unsigned short Vr[64][64];
  __shared__ __align__(16) unsigned short Vp[64][64];
  __shared__ __align__(16) unsigned short Pr[64][32];
  __shared__ __align__(16) unsigned short Pp[64][32];

  const int tid  = threadIdx.x;
  const int wq   = tid >> 6, lane = tid & 63;
  const int lrow = lane & 15, lgrp = lane >> 4;

  // XCD swizzle: 128 consecutive logical blocks (2 batch-heads) per XCD;
  // the two halves of a qtile are adjacent -> same XCD L2.
  const int hw = blockIdx.x;
  const int logical = (hw & 7) * 128 + (hw >> 3);
  const int b = logical >> 6, qtile = (logical >> 1) & 31, half = logical & 1;

  const size_t bo = (size_t)b * SEQ * DK;
  const float* qrb = qr + bo; const float* qpb = qp + bo;
  const float* krb = kr + bo; const float* kpb = kp + bo;
  const float* vrb = vr + bo; const float* vpb = vp + bo;

  float* outR = dout;
  float* outP = dout + (size_t)BQ * DK;
  float* attn = dout + (size_t)2 * BQ * DK + ((size_t)b * SEQ + (size_t)qtile * 64) * SEQ;

  const int qrow = qtile * 64 + wq * 16 + lrow;
  bf16x8 aQ0, aQ1, aQ2, aQ3;
  {
    const float* pr0 = qrb + (size_t)qrow * DK + lgrp * 8;
    const float* pp0 = qpb + (size_t)qrow * DK + lgrp * 8;
    aQ0 = fragld(pr0);
    aQ1 = fragld(pr0 + 32);
    aQ2 = fragld(pp0);
    aQ3 = fragld(pp0 + 32);
  }

  const int skK = tid >> 2, sdp = tid & 3;        // K staging
  const int skV = tid & 15, sdV = (tid >> 4) * 4; // V staging
  const int qloc = wq * 16 + lgrp * 4;

  // total row sums = sum of the 4 slice partials; invert once
  float iR[4], iP[4];
  {
    const size_t base = (size_t)b * SEQ + qtile * 64 + qloc;
    #pragma unroll
    for (int r = 0; r < 4; ++r) {
      float sR = 0.f, sP = 0.f;
      #pragma unroll
      for (int z = 0; z < 4; ++z) {
        sR += wsums[(size_t)(z * 2 + 0) * BQ + base + r];
        sP += wsums[(size_t)(z * 2 + 1) * BQ + base + r];
      }
      iR[r] = 1.0f / sR;
      iP[r] = 1.0f / sP;
    }
  }

  // V prefetch registers (live across compute phase)
  f32x4 va0, va1, va2, va3, vc0, vc1, vc2, vc3;
  auto loadV = [&](int k0) {
    const float* v0  = vrb + (size_t)(k0 + skV) * DK + sdV;
    const float* c0p = vpb + (size_t)(k0 + skV) * DK + sdV;
    va0 = *(const f32x4*)(v0);
    va1 = *(const f32x4*)(v0 + 16 * DK);
    va2 = *(const f32x4*)(v0 + 32 * DK);
    va3 = *(const f32x4*)(v0 + 48 * DK);
    vc0 = *(const f32x4*)(c0p);
    vc1 = *(const f32x4*)(c0p + 16 * DK);
    vc2 = *(const f32x4*)(c0p + 32 * DK);
    vc3 = *(const f32x4*)(c0p + 48 * DK);
  };
  auto storeV = [&]() {
    #pragma unroll
    for (int pass = 0; pass < 4; ++pass) {
      const f32x4 a = pass == 0 ? va0 : pass == 1 ? va1 : pass == 2 ? va2 : va3;
      const f32x4 c = pass == 0 ? vc0 : pass == 1 ? vc1 : pass == 2 ? vc2 : vc3;
      const int key = pass * 16 + skV;
      const int kc = key >> 3, kl = key & 7;
      #pragma unroll
      for (int j = 0; j < 4; ++j) {
        const int d = sdV + j;
        Vr[d][(kc ^ (d & 7)) * 8 + kl] = bfbits(a[j]);
        Vp[d][(kc ^ (d & 7)) * 8 + kl] = bfbits(c[j]);
      }
    }
  };

  const u16x8 SGN = {0x8000, 0x8000, 0x8000, 0x8000, 0x8000, 0x8000, 0x8000, 0x8000};
  f32x4 accR[4] = {}, accP[4] = {};
  const int kbase = half * 1024;

  loadV(kbase);
  for (int i = 0; i < 16; ++i) {
    const int k0 = kbase + i * 64;
    __syncthreads();            // previous compute done with LDS
    { // K loads in-phase (L2-warm); V already in registers
      const int c0 = sdp * 2, c1 = sdp * 2 + 1, sw = skK & 7;
      const float* gr = krb + (size_t)(k0 + skK) * DK + sdp * 16;
      f32x4 r0 = ((const f32x4*)gr)[0], r1 = ((const f32x4*)gr)[1];
      f32x4 r2 = ((const f32x4*)gr)[2], r3 = ((const f32x4*)gr)[3];
      const float* gp = kpb + (size_t)(k0 + skK) * DK + sdp * 16;
      f32x4 p0 = ((const f32x4*)gp)[0], p1 = ((const f32x4*)gp)[1];
      f32x4 p2 = ((const f32x4*)gp)[2], p3 = ((const f32x4*)gp)[3];
      storeV();                 // LDS scatter overlaps K loads in flight
      cvt_store(&Kr[skK][(c0 ^ sw) * 8], r0, r1);
      cvt_store(&Kr[skK][(c1 ^ sw) * 8], r2, r3);
      cvt_store(&Kp[skK][(c0 ^ sw) * 8], p0, p1);
      cvt_store(&Kp[skK][(c1 ^ sw) * 8], p2, p3);
    }
    __syncthreads();            // staged tile visible
    if (i < 15) loadV(k0 + 64); // T14: V latency hidden by compute

    #pragma unroll
    for (int h = 0; h < 2; ++h) {
      #pragma unroll
      for (int t = 0; t < 2; ++t) {
        const int key16 = (h * 2 + t) * 16 + lrow;
        const int swk = lrow & 7;
        bf16x8 b0 = __builtin_bit_cast(bf16x8, *(const u16x8*)&Kr[key16][((lgrp    ) ^ swk) * 8]);
        bf16x8 b1 = __builtin_bit_cast(bf16x8, *(const u16x8*)&Kr[key16][((lgrp + 4) ^ swk) * 8]);
        bf16x8 b2 = __builtin_bit_cast(bf16x8, *(const u16x8*)&Kp[key16][((lgrp    ) ^ swk) * 8]);
        bf16x8 b3 = __builtin_bit_cast(bf16x8, *(const u16x8*)&Kp[key16][((lgrp + 4) ^ swk) * 8]);
        f32x4 t1 = {}, t2 = {}, sp = {};
        t1 = MFMA16(aQ0, b0, t1); t1 = MFMA16(aQ1, b1, t1);
        t2 = MFMA16(aQ2, b2, t2); t2 = MFMA16(aQ3, b3, t2);
        sp = MFMA16(aQ0, b2, sp); sp = MFMA16(aQ1, b3, sp);
        sp = MFMA16(aQ2, b0, sp); sp = MFMA16(aQ3, b1, sp);
        #pragma unroll
        for (int r = 0; r < 4; ++r) {
          const float er = __expf((t1[r] - t2[r]) * 0.125f) * iR[r];
          const float ep = __expf(sp[r] * 0.125f) * iP[r];
          const int row = qloc + r, col = t * 16 + lrow;
          const int pc = ((col >> 3) ^ (row & 3)) * 8 + (col & 7);
          Pr[row][pc] = bfbits(er);   // wave-private rows: no barrier
          Pp[row][pc] = bfbits(ep);
        }
      }
      { // PV: accR += Pr.Vr + (-Pp).Vp ; accP += Pr.Vp + Pp.Vr
        const int prow = wq * 16 + lrow;
        u16x8 uar = *(const u16x8*)&Pr[prow][(lgrp ^ (prow & 3)) * 8];
        u16x8 uap = *(const u16x8*)&Pp[prow][(lgrp ^ (prow & 3)) * 8];
        u16x8 uan = uap ^ SGN;
        bf16x8 apr = __builtin_bit_cast(bf16x8, uar);
        bf16x8 app = __builtin_bit_cast(bf16x8, uap);
        bf16x8 apn = __builtin_bit_cast(bf16x8, uan);
        #pragma unroll
        for (int nt = 0; nt < 4; ++nt) {
          const int d = nt * 16 + lrow;
          const int cv = ((h * 4 + lgrp) ^ (d & 7)) * 8;
          bf16x8 bvr = __builtin_bit_cast(bf16x8, *(const u16x8*)&Vr[d][cv]);
          bf16x8 bvp = __builtin_bit_cast(bf16x8, *(const u16x8*)&Vp[d][cv]);
          accR[nt] = MFMA16(apr, bvr, accR[nt]);
          accR[nt] = MFMA16(apn, bvp, accR[nt]);
          accP[nt] = MFMA16(apr, bvp, accP[nt]);
          accP[nt] = MFMA16(app, bvr, accP[nt]);
        }
      }
      { // attn write: FULL 128B lines (8 lanes x 16B per row), NT
        const int j8 = lane & 7;
        #pragma unroll
        for (int s = 0; s < 2; ++s) {
          const int arow = wq * 16 + s * 8 + (lane >> 3);
          const int pc = (((j8 >> 1) ^ (arow & 3)) * 8) + (j8 & 1) * 4;
          u16x4 ua = *(const u16x4*)&Pr[arow][pc];
          f32x4 fa;
          #pragma unroll
          for (int q = 0; q < 4; ++q)
            fa[q] = __builtin_bit_cast(float, (unsigned)ua[q] << 16);
          float* dst = attn + (size_t)arow * SEQ + k0 + h * 32 + j8 * 4;
          __builtin_nontemporal_store(fa, (f32x4*)dst);
        }
      }
    }
  }

  // ---- O: atomicAdd partials (exactly 2 contributors/elem -> deterministic) ----
  #pragma unroll
  for (int nt = 0; nt < 4; ++nt) {
    const int d = nt * 16 + lrow;
    #pragma unroll
    for (int r = 0; r < 4; ++r) {
      const size_t o = ((size_t)b * SEQ + qtile * 64 + qloc + r) * DK + d;
      atomicAdd(&outR[o], accR[nt][r]);
      atomicAdd(&outP[o], accP[nt][r]);
    }
  }
}

extern "C" void kernel_launch(void* const* d_in, const int* in_sizes, int n_in,
                              void* d_out, int out_size, void* d_ws, size_t ws_size,
                              hipStream_t stream)
{
  const float* qr = (const float*)d_in[0];
  const float* kr = (const float*)d_in[1];
  const float* vr = (const float*)d_in[2];
  const float* qp = (const float*)d_in[3];
  const float* kp = (const float*)d_in[4];
  const float* vp = (const float*)d_in[5];
  float* out = (float*)d_out;
  float* wsums = (float*)d_ws;   // 8*BQ floats = 1MB partial sums

  // zero the O region (atomics accumulate into it); attn region fully overwritten
  hipMemsetAsync(out, 0, (size_t)2 * BQ * DK * sizeof(float), stream);

  ck_sums<<<4 * SEQ / 64 * BATCH, 256, 0, stream>>>(qr, kr, qp, kp, wsums);
  ck_main<<<2 * SEQ / 64 * BATCH, 256, 0, stream>>>(qr, kr, vr, qp, kp, vp, wsums, out);
}

// Round 7
// 254.944 us; speedup vs baseline: 3.0595x; 1.8826x over previous
//
#include <hip/hip_runtime.h>
#include <hip/hip_bf16.h>
#include <stdint.h>

#define BATCH 16
#define SEQ   2048
#define DK    64
#define BQ    (BATCH * SEQ)
#define MAT   ((size_t)BQ * DK)      // 2.1M elems per output matrix

typedef float  f32x4  __attribute__((ext_vector_type(4)));
typedef __bf16 bf16x8 __attribute__((ext_vector_type(8)));
typedef unsigned short u16x8 __attribute__((ext_vector_type(8)));
typedef unsigned short u16x4 __attribute__((ext_vector_type(4)));

#define MFMA16(a, b, c) __builtin_amdgcn_mfma_f32_16x16x32_bf16((a), (b), (c), 0, 0, 0)

// ws tile block layout per (bh, tile): 16384 u16 = 32KB:
//   [Kr 64x64][Kp 64x64][Vr^T 64x64][Vp^T 64x64], all chunk-swizzled for LDS.
#define TILEU 16384

__device__ __forceinline__ unsigned short bfbits(float f) {
  return __builtin_bit_cast(unsigned short, __float2bfloat16(f));
}

__device__ __forceinline__ bf16x8 fragld(const float* p) {
  f32x4 a = *(const f32x4*)p;
  f32x4 c = *(const f32x4*)(p + 4);
  bf16x8 r;
  r[0] = (__bf16)a[0]; r[1] = (__bf16)a[1]; r[2] = (__bf16)a[2]; r[3] = (__bf16)a[3];
  r[4] = (__bf16)c[0]; r[5] = (__bf16)c[1]; r[6] = (__bf16)c[2]; r[7] = (__bf16)c[3];
  return r;
}

__device__ __forceinline__ void cvt_store(unsigned short* dst, f32x4 a, f32x4 c) {
  u16x8 v;
  v[0] = bfbits(a[0]); v[1] = bfbits(a[1]); v[2] = bfbits(a[2]); v[3] = bfbits(a[3]);
  v[4] = bfbits(c[0]); v[5] = bfbits(c[1]); v[6] = bfbits(c[2]); v[7] = bfbits(c[3]);
  *(u16x8*)dst = v;
}

// async global(16B/lane) -> LDS; dest = wave-uniform base + lane*16
__device__ __forceinline__ void gload16(const unsigned short* g, unsigned short* l) {
  __builtin_amdgcn_global_load_lds(
      (const __attribute__((address_space(1))) void*)g,
      (__attribute__((address_space(3))) void*)l, 16, 0, 0);
}

// ---------------- Kernel 0: K/V -> bf16 swizzled tiles in ws ----------------
// One block per (bh, tile). K: row-major, column-chunk XOR swizzle.
// V: transposed (d-major) + swizzle, via LDS.
__global__ __launch_bounds__(256)
void ck_convert(const float* __restrict__ kr, const float* __restrict__ kp,
                const float* __restrict__ vr, const float* __restrict__ vp,
                unsigned short* __restrict__ kv)
{
  __shared__ __align__(16) unsigned short VL[8192];  // Vr(4096) Vp(4096)
  const int b = blockIdx.x >> 5, tile = blockIdx.x & 31;
  const int tid = threadIdx.x;
  unsigned short* blk = kv + (size_t)(b * 32 + tile) * TILEU;
  const size_t go = ((size_t)b * SEQ + tile * 64) * DK;

  { // K: each thread one row x 16 cols
    const int row = tid >> 2, cp = tid & 3, sw = row & 7;
    const int c0 = cp * 2, c1 = cp * 2 + 1;
    const float* gr = kr + go + (size_t)row * DK + cp * 16;
    f32x4 r0 = ((const f32x4*)gr)[0], r1 = ((const f32x4*)gr)[1];
    f32x4 r2 = ((const f32x4*)gr)[2], r3 = ((const f32x4*)gr)[3];
    const float* gp = kp + go + (size_t)row * DK + cp * 16;
    f32x4 p0 = ((const f32x4*)gp)[0], p1 = ((const f32x4*)gp)[1];
    f32x4 p2 = ((const f32x4*)gp)[2], p3 = ((const f32x4*)gp)[3];
    cvt_store(blk + row * 64 + (c0 ^ sw) * 8, r0, r1);
    cvt_store(blk + row * 64 + (c1 ^ sw) * 8, r2, r3);
    cvt_store(blk + 4096 + row * 64 + (c0 ^ sw) * 8, p0, p1);
    cvt_store(blk + 4096 + row * 64 + (c1 ^ sw) * 8, p2, p3);
  }
  { // V: transpose+swizzle through LDS
    const int key = tid & 15, d0 = (tid >> 4) * 4;
    #pragma unroll
    for (int pass = 0; pass < 4; ++pass) {
      const int kk = pass * 16 + key;
      f32x4 a = *(const f32x4*)(vr + go + (size_t)kk * DK + d0);
      f32x4 c = *(const f32x4*)(vp + go + (size_t)kk * DK + d0);
      const int kc = kk >> 3, kl = kk & 7;
      #pragma unroll
      for (int j = 0; j < 4; ++j) {
        const int d = d0 + j;
        VL[d * 64 + (kc ^ (d & 7)) * 8 + kl]        = bfbits(a[j]);
        VL[4096 + d * 64 + (kc ^ (d & 7)) * 8 + kl] = bfbits(c[j]);
      }
    }
  }
  __syncthreads();
  #pragma unroll
  for (int it = 0; it < 4; ++it)  // linear coalesced dump LDS -> ws
    *(u16x8*)(blk + 8192 + it * 2048 + tid * 8) = *(const u16x8*)(VL + it * 2048 + tid * 8);
}

// ---------------- Kernel 1: partial row sums ----------------
// One block = 64 q-rows x one 512-key slice. 2048 blocks, 16KB LDS ->
// 8 blocks/CU. K staged by global_load_lds (already bf16+swizzled in ws).
// No max-subtraction: |S|/8 <~ 6 fits f32 exp.
__global__ __launch_bounds__(256, 8)
void ck_sums(const float* __restrict__ qr, const float* __restrict__ qp,
             const unsigned short* __restrict__ kv, float* __restrict__ wsums)
{
  __shared__ __align__(16) unsigned short KT[8192];  // Kr(4096) Kp(4096)

  const int tid  = threadIdx.x;
  const int wq   = tid >> 6, lane = tid & 63;
  const int lrow = lane & 15, lgrp = lane >> 4;

  const int hw = blockIdx.x;                       // XCD swizzle (2048 = 8*256)
  const int logical = (hw & 7) * 256 + (hw >> 3);
  const int b = logical >> 7, qtile = (logical >> 2) & 31, slice = logical & 3;

  const size_t bo = (size_t)b * SEQ * DK;
  const int qrow = qtile * 64 + wq * 16 + lrow;
  bf16x8 aQ0, aQ1, aQ2, aQ3;
  {
    const float* pr0 = qr + bo + (size_t)qrow * DK + lgrp * 8;
    const float* pp0 = qp + bo + (size_t)qrow * DK + lgrp * 8;
    aQ0 = fragld(pr0);       // q_r d[0:32)
    aQ1 = fragld(pr0 + 32);  // q_r d[32:64)
    aQ2 = fragld(pp0);       // q_p d[0:32)
    aQ3 = fragld(pp0 + 32);  // q_p d[32:64)
  }

  float lsR[4] = {0.f, 0.f, 0.f, 0.f};
  float lsP[4] = {0.f, 0.f, 0.f, 0.f};

  for (int i = 0; i < 8; ++i) {
    const int tile = slice * 8 + i;
    const unsigned short* src = kv + (size_t)(b * 32 + tile) * TILEU;  // K at +0
    __syncthreads();
    #pragma unroll
    for (int c = 0; c < 4; ++c) {   // 16KB = 16 x 1KB chunks, 4 per wave
      const int ch = wq * 4 + c;
      gload16(src + ch * 512 + lane * 8, KT + ch * 512);
    }
    asm volatile("s_waitcnt vmcnt(0)" ::: "memory");
    __syncthreads();
    #pragma unroll
    for (int t = 0; t < 4; ++t) {
      const int key16 = t * 16 + lrow;
      const int swk = lrow & 7;
      bf16x8 b0 = __builtin_bit_cast(bf16x8, *(const u16x8*)&KT[key16 * 64 + ((lgrp    ) ^ swk) * 8]);
      bf16x8 b1 = __builtin_bit_cast(bf16x8, *(const u16x8*)&KT[key16 * 64 + ((lgrp + 4) ^ swk) * 8]);
      bf16x8 b2 = __builtin_bit_cast(bf16x8, *(const u16x8*)&KT[4096 + key16 * 64 + ((lgrp    ) ^ swk) * 8]);
      bf16x8 b3 = __builtin_bit_cast(bf16x8, *(const u16x8*)&KT[4096 + key16 * 64 + ((lgrp + 4) ^ swk) * 8]);
      f32x4 t1 = {}, t2 = {}, sp = {};
      t1 = MFMA16(aQ0, b0, t1); t1 = MFMA16(aQ1, b1, t1);  // q_r.k_r
      t2 = MFMA16(aQ2, b2, t2); t2 = MFMA16(aQ3, b3, t2);  // q_p.k_p
      sp = MFMA16(aQ0, b2, sp); sp = MFMA16(aQ1, b3, sp);  // q_r.k_p
      sp = MFMA16(aQ2, b0, sp); sp = MFMA16(aQ3, b1, sp);  // q_p.k_r
      #pragma unroll
      for (int r = 0; r < 4; ++r) {
        lsR[r] += __expf((t1[r] - t2[r]) * 0.125f);
        lsP[r] += __expf(sp[r] * 0.125f);
      }
    }
  }

  #pragma unroll
  for (int r = 0; r < 4; ++r) {
    float sR = lsR[r], sP = lsP[r];
    #pragma unroll
    for (int m = 1; m < 16; m <<= 1) {
      sR += __shfl_xor(sR, m, 64);
      sP += __shfl_xor(sP, m, 64);
    }
    if (lrow == 0) {
      const size_t row = (size_t)b * SEQ + qtile * 64 + wq * 16 + lgrp * 4 + r;
      wsums[(size_t)(slice * 2 + 0) * BQ + row] = sR;
      wsums[(size_t)(slice * 2 + 1) * BQ + row] = sP;
    }
  }
}

// ---------------- Kernel 2: PV + normalized attn ----------------
// One block = 64 q-rows x one 1024-key half; 1024 blocks, 40KB LDS ->
// 4 blocks/CU. K+V staged by global_load_lds from ws (bf16, pre-swizzled).
// attn written once, normalized, full 128B lines, NT. Partial O -> ws.
__global__ __launch_bounds__(256, 4)
void ck_main(const float* __restrict__ qr, const float* __restrict__ qp,
             const unsigned short* __restrict__ kv,
             const float* __restrict__ wsums, float* __restrict__ wsO,
             float* __restrict__ dout)
{
  __shared__ __align__(16) unsigned short KV[16384];      // Kr,Kp,Vr,Vp (32KB)
  __shared__ __align__(16) unsigned short Pr[64][32], Pp[64][32];

  const int tid  = threadIdx.x;
  const int wq   = tid >> 6, lane = tid & 63;
  const int lrow = lane & 15, lgrp = lane >> 4;

  const int hw = blockIdx.x;                       // XCD swizzle (1024 = 8*128)
  const int logical = (hw & 7) * 128 + (hw >> 3);
  const int b = logical >> 6, qtile = (logical >> 1) & 31, half = logical & 1;

  const size_t bo = (size_t)b * SEQ * DK;
  float* attn = dout + 2 * MAT + ((size_t)b * SEQ + (size_t)qtile * 64) * SEQ;

  const int qrow = qtile * 64 + wq * 16 + lrow;
  bf16x8 aQ0, aQ1, aQ2, aQ3;
  {
    const float* pr0 = qr + bo + (size_t)qrow * DK + lgrp * 8;
    const float* pp0 = qp + bo + (size_t)qrow * DK + lgrp * 8;
    aQ0 = fragld(pr0);
    aQ1 = fragld(pr0 + 32);
    aQ2 = fragld(pp0);
    aQ3 = fragld(pp0 + 32);
  }

  const int qloc = wq * 16 + lgrp * 4;
  float iR[4], iP[4];
  {
    const size_t base = (size_t)b * SEQ + qtile * 64 + qloc;
    #pragma unroll
    for (int r = 0; r < 4; ++r) {
      float sR = 0.f, sP = 0.f;
      #pragma unroll
      for (int z = 0; z < 4; ++z) {
        sR += wsums[(size_t)(z * 2 + 0) * BQ + base + r];
        sP += wsums[(size_t)(z * 2 + 1) * BQ + base + r];
      }
      iR[r] = 1.0f / sR;
      iP[r] = 1.0f / sP;
    }
  }

  const u16x8 SGN = {0x8000, 0x8000, 0x8000, 0x8000, 0x8000, 0x8000, 0x8000, 0x8000};
  f32x4 accR[4] = {}, accP[4] = {};

  for (int i = 0; i < 16; ++i) {
    const int tile = half * 16 + i;
    const int k0 = tile * 64;
    const unsigned short* src = kv + (size_t)(b * 32 + tile) * TILEU;
    __syncthreads();
    #pragma unroll
    for (int c = 0; c < 8; ++c) {   // 32KB = 32 x 1KB chunks, 8 per wave
      const int ch = wq * 8 + c;
      gload16(src + ch * 512 + lane * 8, KV + ch * 512);
    }
    asm volatile("s_waitcnt vmcnt(0)" ::: "memory");
    __syncthreads();

    #pragma unroll
    for (int h = 0; h < 2; ++h) {
      #pragma unroll
      for (int t = 0; t < 2; ++t) {
        const int key16 = (h * 2 + t) * 16 + lrow;
        const int swk = lrow & 7;
        bf16x8 b0 = __builtin_bit_cast(bf16x8, *(const u16x8*)&KV[key16 * 64 + ((lgrp    ) ^ swk) * 8]);
        bf16x8 b1 = __builtin_bit_cast(bf16x8, *(const u16x8*)&KV[key16 * 64 + ((lgrp + 4) ^ swk) * 8]);
        bf16x8 b2 = __builtin_bit_cast(bf16x8, *(const u16x8*)&KV[4096 + key16 * 64 + ((lgrp    ) ^ swk) * 8]);
        bf16x8 b3 = __builtin_bit_cast(bf16x8, *(const u16x8*)&KV[4096 + key16 * 64 + ((lgrp + 4) ^ swk) * 8]);
        f32x4 t1 = {}, t2 = {}, sp = {};
        t1 = MFMA16(aQ0, b0, t1); t1 = MFMA16(aQ1, b1, t1);
        t2 = MFMA16(aQ2, b2, t2); t2 = MFMA16(aQ3, b3, t2);
        sp = MFMA16(aQ0, b2, sp); sp = MFMA16(aQ1, b3, sp);
        sp = MFMA16(aQ2, b0, sp); sp = MFMA16(aQ3, b1, sp);
        #pragma unroll
        for (int r = 0; r < 4; ++r) {
          const float er = __expf((t1[r] - t2[r]) * 0.125f) * iR[r];
          const float ep = __expf(sp[r] * 0.125f) * iP[r];
          const int row = qloc + r, col = t * 16 + lrow;
          const int pc = ((col >> 3) ^ (row & 3)) * 8 + (col & 7);
          Pr[row][pc] = bfbits(er);   // wave-private rows: no barrier
          Pp[row][pc] = bfbits(ep);
        }
      }
      { // PV: accR += Pr.Vr + (-Pp).Vp ; accP += Pr.Vp + Pp.Vr
        const int prow = wq * 16 + lrow;
        u16x8 uar = *(const u16x8*)&Pr[prow][(lgrp ^ (prow & 3)) * 8];
        u16x8 uap = *(const u16x8*)&Pp[prow][(lgrp ^ (prow & 3)) * 8];
        u16x8 uan = uap ^ SGN;
        bf16x8 apr = __builtin_bit_cast(bf16x8, uar);
        bf16x8 app = __builtin_bit_cast(bf16x8, uap);
        bf16x8 apn = __builtin_bit_cast(bf16x8, uan);
        #pragma unroll
        for (int nt = 0; nt < 4; ++nt) {
          const int d = nt * 16 + lrow;
          const int cv = ((h * 4 + lgrp) ^ (d & 7)) * 8;
          bf16x8 bvr = __builtin_bit_cast(bf16x8, *(const u16x8*)&KV[8192  + d * 64 + cv]);
          bf16x8 bvp = __builtin_bit_cast(bf16x8, *(const u16x8*)&KV[12288 + d * 64 + cv]);
          accR[nt] = MFMA16(apr, bvr, accR[nt]);
          accR[nt] = MFMA16(apn, bvp, accR[nt]);
          accP[nt] = MFMA16(apr, bvp, accP[nt]);
          accP[nt] = MFMA16(app, bvr, accP[nt]);
        }
      }
      { // attn write: full 128B lines (8 lanes x 16B per row), NT
        const int j8 = lane & 7;
        #pragma unroll
        for (int s = 0; s < 2; ++s) {
          const int arow = wq * 16 + s * 8 + (lane >> 3);
          const int pc = (((j8 >> 1) ^ (arow & 3)) * 8) + (j8 & 1) * 4;
          u16x4 ua = *(const u16x4*)&Pr[arow][pc];
          f32x4 fa;
          #pragma unroll
          for (int q = 0; q < 4; ++q)
            fa[q] = __builtin_bit_cast(float, (unsigned)ua[q] << 16);
          float* dst = attn + (size_t)arow * SEQ + k0 + h * 32 + j8 * 4;
          __builtin_nontemporal_store(fa, (f32x4*)dst);
        }
      }
    }
  }

  // ---- partial O -> ws (deterministic; combined by ck_combine) ----
  #pragma unroll
  for (int nt = 0; nt < 4; ++nt) {
    const int d = nt * 16 + lrow;
    #pragma unroll
    for (int r = 0; r < 4; ++r) {
      const size_t o = ((size_t)b * SEQ + qtile * 64 + qloc + r) * DK + d;
      wsO[(size_t)(half * 2 + 0) * MAT + o] = accR[nt][r];
      wsO[(size_t)(half * 2 + 1) * MAT + o] = accP[nt][r];
    }
  }
}

// ---------------- Kernel 3: combine the two half partials ----------------
__global__ __launch_bounds__(256)
void ck_combine(const float* __restrict__ wsO, float* __restrict__ dout)
{
  const size_t i = ((size_t)blockIdx.x * 256 + threadIdx.x) * 4;
  f32x4 r = *(const f32x4*)(wsO + i)       + *(const f32x4*)(wsO + 2 * MAT + i);
  f32x4 p = *(const f32x4*)(wsO + MAT + i) + *(const f32x4*)(wsO + 3 * MAT + i);
  __builtin_nontemporal_store(r, (f32x4*)(dout + i));
  __builtin_nontemporal_store(p, (f32x4*)(dout + MAT + i));
}

extern "C" void kernel_launch(void* const* d_in, const int* in_sizes, int n_in,
                              void* d_out, int out_size, void* d_ws, size_t ws_size,
                              hipStream_t stream)
{
  const float* qr = (const float*)d_in[0];
  const float* kr = (const float*)d_in[1];
  const float* vr = (const float*)d_in[2];
  const float* qp = (const float*)d_in[3];
  const float* kp = (const float*)d_in[4];
  const float* vp = (const float*)d_in[5];
  float* out = (float*)d_out;

  // ws: [kv bf16 tiles 16MB][wsums 1MB][wsO 32MB]
  unsigned short* kv = (unsigned short*)d_ws;
  float* wsums = (float*)((char*)d_ws + (16u << 20));
  float* wsO   = (float*)((char*)d_ws + (17u << 20));

  ck_convert<<<BATCH * 32, 256, 0, stream>>>(kr, kp, vr, vp, kv);
  ck_sums<<<4 * 32 * BATCH, 256, 0, stream>>>(qr, qp, kv, wsums);
  ck_main<<<2 * 32 * BATCH, 256, 0, stream>>>(qr, qp, kv, wsums, wsO, out);
  ck_combine<<<(unsigned)(MAT / 4 / 256), 256, 0, stream>>>(wsO, out);
}

// Round 8
// 154.552 us; speedup vs baseline: 5.0468x; 1.6496x over previous
//
#include <hip/hip_runtime.h>
#include <hip/hip_bf16.h>
#include <stdint.h>

#define BATCH 16
#define SEQ   2048
#define DK    64
#define BQ    (BATCH * SEQ)
#define MAT   ((size_t)BQ * DK)      // 2.1M elems per output matrix

typedef float  f32x4  __attribute__((ext_vector_type(4)));
typedef __bf16 bf16x8 __attribute__((ext_vector_type(8)));
typedef unsigned short u16x8 __attribute__((ext_vector_type(8)));
typedef unsigned short u16x4 __attribute__((ext_vector_type(4)));

#define MFMA16(a, b, c) __builtin_amdgcn_mfma_f32_16x16x32_bf16((a), (b), (c), 0, 0, 0)

// ws tile block layout per (bh, tile): 16384 u16 = 32KB:
//   [Kr 64x64][Kp 64x64][Vr^T 64x64][Vp^T 64x64], all chunk-swizzled for LDS.
#define TILEU 16384

__device__ __forceinline__ unsigned short bfbits(float f) {
  return __builtin_bit_cast(unsigned short, __float2bfloat16(f));
}

__device__ __forceinline__ void cvt_store(unsigned short* dst, f32x4 a, f32x4 c) {
  u16x8 v;
  v[0] = bfbits(a[0]); v[1] = bfbits(a[1]); v[2] = bfbits(a[2]); v[3] = bfbits(a[3]);
  v[4] = bfbits(c[0]); v[5] = bfbits(c[1]); v[6] = bfbits(c[2]); v[7] = bfbits(c[3]);
  *(u16x8*)dst = v;
}

// async global(16B/lane) -> LDS; dest = wave-uniform base + lane*16
__device__ __forceinline__ void gload16(const unsigned short* g, unsigned short* l) {
  __builtin_amdgcn_global_load_lds(
      (const __attribute__((address_space(1))) void*)g,
      (__attribute__((address_space(3))) void*)l, 16, 0, 0);
}

// ---------------- Kernel 0a: K/V -> bf16 swizzled tiles in ws ----------------
__global__ __launch_bounds__(256)
void ck_convert(const float* __restrict__ kr, const float* __restrict__ kp,
                const float* __restrict__ vr, const float* __restrict__ vp,
                unsigned short* __restrict__ kv)
{
  __shared__ __align__(16) unsigned short VL[8192];  // Vr(4096) Vp(4096)
  const int b = blockIdx.x >> 5, tile = blockIdx.x & 31;
  const int tid = threadIdx.x;
  unsigned short* blk = kv + (size_t)(b * 32 + tile) * TILEU;
  const size_t go = ((size_t)b * SEQ + tile * 64) * DK;

  { // K: each thread one row x 16 cols
    const int row = tid >> 2, cp = tid & 3, sw = row & 7;
    const int c0 = cp * 2, c1 = cp * 2 + 1;
    const float* gr = kr + go + (size_t)row * DK + cp * 16;
    f32x4 r0 = ((const f32x4*)gr)[0], r1 = ((const f32x4*)gr)[1];
    f32x4 r2 = ((const f32x4*)gr)[2], r3 = ((const f32x4*)gr)[3];
    const float* gp = kp + go + (size_t)row * DK + cp * 16;
    f32x4 p0 = ((const f32x4*)gp)[0], p1 = ((const f32x4*)gp)[1];
    f32x4 p2 = ((const f32x4*)gp)[2], p3 = ((const f32x4*)gp)[3];
    cvt_store(blk + row * 64 + (c0 ^ sw) * 8, r0, r1);
    cvt_store(blk + row * 64 + (c1 ^ sw) * 8, r2, r3);
    cvt_store(blk + 4096 + row * 64 + (c0 ^ sw) * 8, p0, p1);
    cvt_store(blk + 4096 + row * 64 + (c1 ^ sw) * 8, p2, p3);
  }
  { // V: transpose+swizzle through LDS
    const int key = tid & 15, d0 = (tid >> 4) * 4;
    #pragma unroll
    for (int pass = 0; pass < 4; ++pass) {
      const int kk = pass * 16 + key;
      f32x4 a = *(const f32x4*)(vr + go + (size_t)kk * DK + d0);
      f32x4 c = *(const f32x4*)(vp + go + (size_t)kk * DK + d0);
      const int kc = kk >> 3, kl = kk & 7;
      #pragma unroll
      for (int j = 0; j < 4; ++j) {
        const int d = d0 + j;
        VL[d * 64 + (kc ^ (d & 7)) * 8 + kl]        = bfbits(a[j]);
        VL[4096 + d * 64 + (kc ^ (d & 7)) * 8 + kl] = bfbits(c[j]);
      }
    }
  }
  __syncthreads();
  #pragma unroll
  for (int it = 0; it < 4; ++it)  // linear coalesced dump LDS -> ws
    *(u16x8*)(blk + 8192 + it * 2048 + tid * 8) = *(const u16x8*)(VL + it * 2048 + tid * 8);
}

// ---------------- Kernel 0b: Q -> bf16 (row-major) in ws ----------------
__global__ __launch_bounds__(256)
void ck_qconv(const float* __restrict__ qr, const float* __restrict__ qp,
              unsigned short* __restrict__ qb)
{
  const size_t i8 = ((size_t)blockIdx.x * 256 + threadIdx.x) * 8;
  const float* src = (i8 < MAT) ? qr : qp;
  const size_t off = (i8 < MAT) ? i8 : i8 - MAT;
  f32x4 a = *(const f32x4*)(src + off);
  f32x4 c = *(const f32x4*)(src + off + 4);
  cvt_store(qb + i8, a, c);
}

// ---------------- Kernel 1: partial row sums (pipelined) ----------------
// One block = 64 q-rows x one 512-key slice. 2048 blocks, 32KB LDS (double
// buffer) -> 5 blocks/CU. Counted vmcnt(4): next tile's loads stay in flight
// across both barriers (T3/T4-lite). No max-subtraction: |S|/8 <~ 6.
__global__ __launch_bounds__(256, 4)
void ck_sums(const unsigned short* __restrict__ qb,
             const unsigned short* __restrict__ kv, float* __restrict__ wsums)
{
  __shared__ __align__(16) unsigned short KT[2][8192];  // per buf: Kr(4096) Kp(4096)

  const int tid  = threadIdx.x;
  const int wq   = tid >> 6, lane = tid & 63;
  const int lrow = lane & 15, lgrp = lane >> 4;

  const int hw = blockIdx.x;                       // XCD swizzle (2048 = 8*256)
  const int logical = (hw & 7) * 256 + (hw >> 3);
  const int b = logical >> 7, qtile = (logical >> 2) & 31, slice = logical & 3;

  const int qrow = qtile * 64 + wq * 16 + lrow;
  const size_t qoff = ((size_t)b * SEQ + qrow) * DK;
  bf16x8 aQ0 = __builtin_bit_cast(bf16x8, *(const u16x8*)(qb + qoff + lgrp * 8));
  bf16x8 aQ1 = __builtin_bit_cast(bf16x8, *(const u16x8*)(qb + qoff + 32 + lgrp * 8));
  bf16x8 aQ2 = __builtin_bit_cast(bf16x8, *(const u16x8*)(qb + MAT + qoff + lgrp * 8));
  bf16x8 aQ3 = __builtin_bit_cast(bf16x8, *(const u16x8*)(qb + MAT + qoff + 32 + lgrp * 8));

  auto issue = [&](int tile, int buf) {
    const unsigned short* src = kv + (size_t)(b * 32 + tile) * TILEU;  // K at +0
    #pragma unroll
    for (int c = 0; c < 4; ++c) {   // 16KB = 16 x 1KB chunks, 4 per wave
      const int ch = wq * 4 + c;
      gload16(src + ch * 512 + lane * 8, &KT[buf][ch * 512]);
    }
  };

  float lsR[4] = {0.f, 0.f, 0.f, 0.f};
  float lsP[4] = {0.f, 0.f, 0.f, 0.f};

  issue(slice * 8 + 0, 0);
  issue(slice * 8 + 1, 1);
  int cur = 0;
  for (int i = 0; i < 8; ++i) {
    if (i < 7) { asm volatile("s_waitcnt vmcnt(4)" ::: "memory"); }  // leave next tile in flight
    else       { asm volatile("s_waitcnt vmcnt(0)" ::: "memory"); }
    __builtin_amdgcn_sched_barrier(0);
    __syncthreads();                 // whole tile visible (each wave waited its own)

    const unsigned short* KB = KT[cur];
    #pragma unroll
    for (int t = 0; t < 4; ++t) {
      const int key16 = t * 16 + lrow;
      const int swk = lrow & 7;
      bf16x8 b0 = __builtin_bit_cast(bf16x8, *(const u16x8*)&KB[key16 * 64 + ((lgrp    ) ^ swk) * 8]);
      bf16x8 b1 = __builtin_bit_cast(bf16x8, *(const u16x8*)&KB[key16 * 64 + ((lgrp + 4) ^ swk) * 8]);
      bf16x8 b2 = __builtin_bit_cast(bf16x8, *(const u16x8*)&KB[4096 + key16 * 64 + ((lgrp    ) ^ swk) * 8]);
      bf16x8 b3 = __builtin_bit_cast(bf16x8, *(const u16x8*)&KB[4096 + key16 * 64 + ((lgrp + 4) ^ swk) * 8]);
      f32x4 t1 = {}, t2 = {}, sp = {};
      t1 = MFMA16(aQ0, b0, t1); t1 = MFMA16(aQ1, b1, t1);  // q_r.k_r
      t2 = MFMA16(aQ2, b2, t2); t2 = MFMA16(aQ3, b3, t2);  // q_p.k_p
      sp = MFMA16(aQ0, b2, sp); sp = MFMA16(aQ1, b3, sp);  // q_r.k_p
      sp = MFMA16(aQ2, b0, sp); sp = MFMA16(aQ3, b1, sp);  // q_p.k_r
      #pragma unroll
      for (int r = 0; r < 4; ++r) {
        lsR[r] += __expf((t1[r] - t2[r]) * 0.125f);
        lsP[r] += __expf(sp[r] * 0.125f);
      }
    }
    __syncthreads();                 // all waves done reading KT[cur]
    if (i + 2 < 8) issue(slice * 8 + i + 2, cur);
    cur ^= 1;
  }

  #pragma unroll
  for (int r = 0; r < 4; ++r) {
    float sR = lsR[r], sP = lsP[r];
    #pragma unroll
    for (int m = 1; m < 16; m <<= 1) {
      sR += __shfl_xor(sR, m, 64);
      sP += __shfl_xor(sP, m, 64);
    }
    if (lrow == 0) {
      const size_t row = (size_t)b * SEQ + qtile * 64 + wq * 16 + lgrp * 4 + r;
      wsums[(size_t)(slice * 2 + 0) * BQ + row] = sR;
      wsums[(size_t)(slice * 2 + 1) * BQ + row] = sP;
    }
  }
}

// ---------------- Kernel 2: PV + normalized attn ----------------
// One block = 64 q-rows x one 1024-key half; 1024 blocks, 40KB LDS ->
// 4 blocks/CU. K+V staged by global_load_lds from ws (bf16, pre-swizzled).
// attn written once, normalized, full 128B lines, NT. Partial O -> ws.
__global__ __launch_bounds__(256, 4)
void ck_main(const unsigned short* __restrict__ qb,
             const unsigned short* __restrict__ kv,
             const float* __restrict__ wsums, float* __restrict__ wsO,
             float* __restrict__ dout)
{
  __shared__ __align__(16) unsigned short KV[16384];      // Kr,Kp,Vr,Vp (32KB)
  __shared__ __align__(16) unsigned short Pr[64][32], Pp[64][32];

  const int tid  = threadIdx.x;
  const int wq   = tid >> 6, lane = tid & 63;
  const int lrow = lane & 15, lgrp = lane >> 4;

  const int hw = blockIdx.x;                       // XCD swizzle (1024 = 8*128)
  const int logical = (hw & 7) * 128 + (hw >> 3);
  const int b = logical >> 6, qtile = (logical >> 1) & 31, half = logical & 1;

  float* attn = dout + 2 * MAT + ((size_t)b * SEQ + (size_t)qtile * 64) * SEQ;

  const int qrow = qtile * 64 + wq * 16 + lrow;
  const size_t qoff = ((size_t)b * SEQ + qrow) * DK;
  bf16x8 aQ0 = __builtin_bit_cast(bf16x8, *(const u16x8*)(qb + qoff + lgrp * 8));
  bf16x8 aQ1 = __builtin_bit_cast(bf16x8, *(const u16x8*)(qb + qoff + 32 + lgrp * 8));
  bf16x8 aQ2 = __builtin_bit_cast(bf16x8, *(const u16x8*)(qb + MAT + qoff + lgrp * 8));
  bf16x8 aQ3 = __builtin_bit_cast(bf16x8, *(const u16x8*)(qb + MAT + qoff + 32 + lgrp * 8));

  const int qloc = wq * 16 + lgrp * 4;
  float iR[4], iP[4];
  {
    const size_t base = (size_t)b * SEQ + qtile * 64 + qloc;
    #pragma unroll
    for (int r = 0; r < 4; ++r) {
      float sR = 0.f, sP = 0.f;
      #pragma unroll
      for (int z = 0; z < 4; ++z) {
        sR += wsums[(size_t)(z * 2 + 0) * BQ + base + r];
        sP += wsums[(size_t)(z * 2 + 1) * BQ + base + r];
      }
      iR[r] = 1.0f / sR;
      iP[r] = 1.0f / sP;
    }
  }

  const u16x8 SGN = {0x8000, 0x8000, 0x8000, 0x8000, 0x8000, 0x8000, 0x8000, 0x8000};
  f32x4 accR[4] = {}, accP[4] = {};

  for (int i = 0; i < 16; ++i) {
    const int tile = half * 16 + i;
    const int k0 = tile * 64;
    const unsigned short* src = kv + (size_t)(b * 32 + tile) * TILEU;
    __syncthreads();
    #pragma unroll
    for (int c = 0; c < 8; ++c) {   // 32KB = 32 x 1KB chunks, 8 per wave
      const int ch = wq * 8 + c;
      gload16(src + ch * 512 + lane * 8, KV + ch * 512);
    }
    asm volatile("s_waitcnt vmcnt(0)" ::: "memory");
    __builtin_amdgcn_sched_barrier(0);
    __syncthreads();

    #pragma unroll
    for (int h = 0; h < 2; ++h) {
      #pragma unroll
      for (int t = 0; t < 2; ++t) {
        const int key16 = (h * 2 + t) * 16 + lrow;
        const int swk = lrow & 7;
        bf16x8 b0 = __builtin_bit_cast(bf16x8, *(const u16x8*)&KV[key16 * 64 + ((lgrp    ) ^ swk) * 8]);
        bf16x8 b1 = __builtin_bit_cast(bf16x8, *(const u16x8*)&KV[key16 * 64 + ((lgrp + 4) ^ swk) * 8]);
        bf16x8 b2 = __builtin_bit_cast(bf16x8, *(const u16x8*)&KV[4096 + key16 * 64 + ((lgrp    ) ^ swk) * 8]);
        bf16x8 b3 = __builtin_bit_cast(bf16x8, *(const u16x8*)&KV[4096 + key16 * 64 + ((lgrp + 4) ^ swk) * 8]);
        f32x4 t1 = {}, t2 = {}, sp = {};
        t1 = MFMA16(aQ0, b0, t1); t1 = MFMA16(aQ1, b1, t1);
        t2 = MFMA16(aQ2, b2, t2); t2 = MFMA16(aQ3, b3, t2);
        sp = MFMA16(aQ0, b2, sp); sp = MFMA16(aQ1, b3, sp);
        sp = MFMA16(aQ2, b0, sp); sp = MFMA16(aQ3, b1, sp);
        #pragma unroll
        for (int r = 0; r < 4; ++r) {
          const float er = __expf((t1[r] - t2[r]) * 0.125f) * iR[r];
          const float ep = __expf(sp[r] * 0.125f) * iP[r];
          const int row = qloc + r, col = t * 16 + lrow;
          const int pc = ((col >> 3) ^ (row & 3)) * 8 + (col & 7);
          Pr[row][pc] = bfbits(er);   // wave-private rows: no barrier
          Pp[row][pc] = bfbits(ep);
        }
      }
      { // PV: accR += Pr.Vr + (-Pp).Vp ; accP += Pr.Vp + Pp.Vr
        const int prow = wq * 16 + lrow;
        u16x8 uar = *(const u16x8*)&Pr[prow][(lgrp ^ (prow & 3)) * 8];
        u16x8 uap = *(const u16x8*)&Pp[prow][(lgrp ^ (prow & 3)) * 8];
        u16x8 uan = uap ^ SGN;
        bf16x8 apr = __builtin_bit_cast(bf16x8, uar);
        bf16x8 app = __builtin_bit_cast(bf16x8, uap);
        bf16x8 apn = __builtin_bit_cast(bf16x8, uan);
        #pragma unroll
        for (int nt = 0; nt < 4; ++nt) {
          const int d = nt * 16 + lrow;
          const int cv = ((h * 4 + lgrp) ^ (d & 7)) * 8;
          bf16x8 bvr = __builtin_bit_cast(bf16x8, *(const u16x8*)&KV[8192  + d * 64 + cv]);
          bf16x8 bvp = __builtin_bit_cast(bf16x8, *(const u16x8*)&KV[12288 + d * 64 + cv]);
          accR[nt] = MFMA16(apr, bvr, accR[nt]);
          accR[nt] = MFMA16(apn, bvp, accR[nt]);
          accP[nt] = MFMA16(apr, bvp, accP[nt]);
          accP[nt] = MFMA16(app, bvr, accP[nt]);
        }
      }
      { // attn write: full 128B lines (8 lanes x 16B per row), NT
        const int j8 = lane & 7;
        #pragma unroll
        for (int s = 0; s < 2; ++s) {
          const int arow = wq * 16 + s * 8 + (lane >> 3);
          const int pc = (((j8 >> 1) ^ (arow & 3)) * 8) + (j8 & 1) * 4;
          u16x4 ua = *(const u16x4*)&Pr[arow][pc];
          f32x4 fa;
          #pragma unroll
          for (int q = 0; q < 4; ++q)
            fa[q] = __builtin_bit_cast(float, (unsigned)ua[q] << 16);
          float* dst = attn + (size_t)arow * SEQ + k0 + h * 32 + j8 * 4;
          __builtin_nontemporal_store(fa, (f32x4*)dst);
        }
      }
    }
  }

  // ---- partial O -> ws (deterministic; combined by ck_combine) ----
  #pragma unroll
  for (int nt = 0; nt < 4; ++nt) {
    const int d = nt * 16 + lrow;
    #pragma unroll
    for (int r = 0; r < 4; ++r) {
      const size_t o = ((size_t)b * SEQ + qtile * 64 + qloc + r) * DK + d;
      wsO[(size_t)(half * 2 + 0) * MAT + o] = accR[nt][r];
      wsO[(size_t)(half * 2 + 1) * MAT + o] = accP[nt][r];
    }
  }
}

// ---------------- Kernel 3: combine the two half partials ----------------
__global__ __launch_bounds__(256)
void ck_combine(const float* __restrict__ wsO, float* __restrict__ dout)
{
  const size_t i = ((size_t)blockIdx.x * 256 + threadIdx.x) * 4;
  f32x4 r = *(const f32x4*)(wsO + i)       + *(const f32x4*)(wsO + 2 * MAT + i);
  f32x4 p = *(const f32x4*)(wsO + MAT + i) + *(const f32x4*)(wsO + 3 * MAT + i);
  __builtin_nontemporal_store(r, (f32x4*)(dout + i));
  __builtin_nontemporal_store(p, (f32x4*)(dout + MAT + i));
}

extern "C" void kernel_launch(void* const* d_in, const int* in_sizes, int n_in,
                              void* d_out, int out_size, void* d_ws, size_t ws_size,
                              hipStream_t stream)
{
  const float* qr = (const float*)d_in[0];
  const float* kr = (const float*)d_in[1];
  const float* vr = (const float*)d_in[2];
  const float* qp = (const float*)d_in[3];
  const float* kp = (const float*)d_in[4];
  const float* vp = (const float*)d_in[5];
  float* out = (float*)d_out;

  // ws: [kv bf16 tiles 16MB][qb bf16 8MB][wsums 1MB][wsO 32MB]
  unsigned short* kv = (unsigned short*)d_ws;
  unsigned short* qb = (unsigned short*)((char*)d_ws + (16u << 20));
  float* wsums = (float*)((char*)d_ws + (24u << 20));
  float* wsO   = (float*)((char*)d_ws + (25u << 20));

  ck_convert<<<BATCH * 32, 256, 0, stream>>>(kr, kp, vr, vp, kv);
  ck_qconv<<<(unsigned)(2 * MAT / 8 / 256), 256, 0, stream>>>(qr, qp, qb);
  ck_sums<<<4 * 32 * BATCH, 256, 0, stream>>>(qb, kv, wsums);
  ck_main<<<2 * 32 * BATCH, 256, 0, stream>>>(qb, kv, wsums, wsO, out);
  ck_combine<<<(unsigned)(MAT / 4 / 256), 256, 0, stream>>>(wsO, out);
}

// Round 9
// 149.923 us; speedup vs baseline: 5.2026x; 1.0309x over previous
//
#include <hip/hip_runtime.h>
#include <hip/hip_bf16.h>
#include <stdint.h>

#define BATCH 16
#define SEQ   2048
#define DK    64
#define BQ    (BATCH * SEQ)
#define MAT   ((size_t)BQ * DK)      // 2.1M elems per output matrix

typedef float  f32x4  __attribute__((ext_vector_type(4)));
typedef __bf16 bf16x8 __attribute__((ext_vector_type(8)));
typedef unsigned short u16x8 __attribute__((ext_vector_type(8)));
typedef unsigned short u16x4 __attribute__((ext_vector_type(4)));

#define MFMA16(a, b, c) __builtin_amdgcn_mfma_f32_16x16x32_bf16((a), (b), (c), 0, 0, 0)

// ws tile block layout per (bh, tile): 16384 u16 = 32KB:
//   [Kr 64x64][Kp 64x64][Vr^T 64x64][Vp^T 64x64], all chunk-swizzled for LDS.
#define TILEU 16384

__device__ __forceinline__ unsigned short bfbits(float f) {
  return __builtin_bit_cast(unsigned short, __float2bfloat16(f));
}

__device__ __forceinline__ void cvt_store(unsigned short* dst, f32x4 a, f32x4 c) {
  u16x8 v;
  v[0] = bfbits(a[0]); v[1] = bfbits(a[1]); v[2] = bfbits(a[2]); v[3] = bfbits(a[3]);
  v[4] = bfbits(c[0]); v[5] = bfbits(c[1]); v[6] = bfbits(c[2]); v[7] = bfbits(c[3]);
  *(u16x8*)dst = v;
}

// async global(16B/lane) -> LDS; dest = wave-uniform base + lane*16
__device__ __forceinline__ void gload16(const unsigned short* g, unsigned short* l) {
  __builtin_amdgcn_global_load_lds(
      (const __attribute__((address_space(1))) void*)g,
      (__attribute__((address_space(3))) void*)l, 16, 0, 0);
}

// -------- Kernel 0: K/V -> bf16 swizzled tiles; Q -> bf16 rows (merged) --------
__global__ __launch_bounds__(256)
void ck_prep(const float* __restrict__ kr, const float* __restrict__ kp,
             const float* __restrict__ vr, const float* __restrict__ vp,
             const float* __restrict__ qr, const float* __restrict__ qp,
             unsigned short* __restrict__ kv, unsigned short* __restrict__ qb)
{
  __shared__ __align__(16) unsigned short VL[8192];  // Vr(4096) Vp(4096)
  const int tid = threadIdx.x;

  if (blockIdx.x >= BATCH * 32) {  // ---- Q conversion: 8 elems/thread ----
    const size_t i8 = ((size_t)(blockIdx.x - BATCH * 32) * 256 + tid) * 8;
    const float* src = (i8 < MAT) ? qr : qp;
    const size_t off = (i8 < MAT) ? i8 : i8 - MAT;
    f32x4 a = *(const f32x4*)(src + off);
    f32x4 c = *(const f32x4*)(src + off + 4);
    cvt_store(qb + i8, a, c);
    return;
  }

  const int b = blockIdx.x >> 5, tile = blockIdx.x & 31;
  unsigned short* blk = kv + (size_t)(b * 32 + tile) * TILEU;
  const size_t go = ((size_t)b * SEQ + tile * 64) * DK;

  { // K: each thread one row x 16 cols
    const int row = tid >> 2, cp = tid & 3, sw = row & 7;
    const int c0 = cp * 2, c1 = cp * 2 + 1;
    const float* gr = kr + go + (size_t)row * DK + cp * 16;
    f32x4 r0 = ((const f32x4*)gr)[0], r1 = ((const f32x4*)gr)[1];
    f32x4 r2 = ((const f32x4*)gr)[2], r3 = ((const f32x4*)gr)[3];
    const float* gp = kp + go + (size_t)row * DK + cp * 16;
    f32x4 p0 = ((const f32x4*)gp)[0], p1 = ((const f32x4*)gp)[1];
    f32x4 p2 = ((const f32x4*)gp)[2], p3 = ((const f32x4*)gp)[3];
    cvt_store(blk + row * 64 + (c0 ^ sw) * 8, r0, r1);
    cvt_store(blk + row * 64 + (c1 ^ sw) * 8, r2, r3);
    cvt_store(blk + 4096 + row * 64 + (c0 ^ sw) * 8, p0, p1);
    cvt_store(blk + 4096 + row * 64 + (c1 ^ sw) * 8, p2, p3);
  }
  { // V: transpose+swizzle through LDS
    const int key = tid & 15, d0 = (tid >> 4) * 4;
    #pragma unroll
    for (int pass = 0; pass < 4; ++pass) {
      const int kk = pass * 16 + key;
      f32x4 a = *(const f32x4*)(vr + go + (size_t)kk * DK + d0);
      f32x4 c = *(const f32x4*)(vp + go + (size_t)kk * DK + d0);
      const int kc = kk >> 3, kl = kk & 7;
      #pragma unroll
      for (int j = 0; j < 4; ++j) {
        const int d = d0 + j;
        VL[d * 64 + (kc ^ (d & 7)) * 8 + kl]        = bfbits(a[j]);
        VL[4096 + d * 64 + (kc ^ (d & 7)) * 8 + kl] = bfbits(c[j]);
      }
    }
  }
  __syncthreads();
  #pragma unroll
  for (int it = 0; it < 4; ++it)  // linear coalesced dump LDS -> ws
    *(u16x8*)(blk + 8192 + it * 2048 + tid * 8) = *(const u16x8*)(VL + it * 2048 + tid * 8);
}

// ---------------- Kernel 1: partial row sums (pipelined) ----------------
// One block = 64 q-rows x one 512-key slice. 2048 blocks, 32KB LDS (double
// buffer) -> 5 blocks/CU. Counted vmcnt(4): next tile's loads stay in flight
// across both barriers. No max-subtraction: |S|/8 <~ 6 fits f32 exp.
__global__ __launch_bounds__(256, 4)
void ck_sums(const unsigned short* __restrict__ qb,
             const unsigned short* __restrict__ kv, float* __restrict__ wsums)
{
  __shared__ __align__(16) unsigned short KT[2][8192];  // per buf: Kr(4096) Kp(4096)

  const int tid  = threadIdx.x;
  const int wq   = tid >> 6, lane = tid & 63;
  const int lrow = lane & 15, lgrp = lane >> 4;

  const int hw = blockIdx.x;                       // XCD swizzle (2048 = 8*256)
  const int logical = (hw & 7) * 256 + (hw >> 3);
  const int b = logical >> 7, qtile = (logical >> 2) & 31, slice = logical & 3;

  const int qrow = qtile * 64 + wq * 16 + lrow;
  const size_t qoff = ((size_t)b * SEQ + qrow) * DK;
  bf16x8 aQ0 = __builtin_bit_cast(bf16x8, *(const u16x8*)(qb + qoff + lgrp * 8));
  bf16x8 aQ1 = __builtin_bit_cast(bf16x8, *(const u16x8*)(qb + qoff + 32 + lgrp * 8));
  bf16x8 aQ2 = __builtin_bit_cast(bf16x8, *(const u16x8*)(qb + MAT + qoff + lgrp * 8));
  bf16x8 aQ3 = __builtin_bit_cast(bf16x8, *(const u16x8*)(qb + MAT + qoff + 32 + lgrp * 8));

  auto issue = [&](int tile, int buf) {
    const unsigned short* src = kv + (size_t)(b * 32 + tile) * TILEU;  // K at +0
    #pragma unroll
    for (int c = 0; c < 4; ++c) {   // 16KB = 16 x 1KB chunks, 4 per wave
      const int ch = wq * 4 + c;
      gload16(src + ch * 512 + lane * 8, &KT[buf][ch * 512]);
    }
  };

  float lsR[4] = {0.f, 0.f, 0.f, 0.f};
  float lsP[4] = {0.f, 0.f, 0.f, 0.f};

  issue(slice * 8 + 0, 0);
  issue(slice * 8 + 1, 1);
  int cur = 0;
  for (int i = 0; i < 8; ++i) {
    if (i < 7) { asm volatile("s_waitcnt vmcnt(4)" ::: "memory"); }  // next tile stays in flight
    else       { asm volatile("s_waitcnt vmcnt(0)" ::: "memory"); }
    __builtin_amdgcn_sched_barrier(0);
    __syncthreads();                 // whole tile visible (each wave waited its own)

    const unsigned short* KB = KT[cur];
    #pragma unroll
    for (int t = 0; t < 4; ++t) {
      const int key16 = t * 16 + lrow;
      const int swk = lrow & 7;
      bf16x8 b0 = __builtin_bit_cast(bf16x8, *(const u16x8*)&KB[key16 * 64 + ((lgrp    ) ^ swk) * 8]);
      bf16x8 b1 = __builtin_bit_cast(bf16x8, *(const u16x8*)&KB[key16 * 64 + ((lgrp + 4) ^ swk) * 8]);
      bf16x8 b2 = __builtin_bit_cast(bf16x8, *(const u16x8*)&KB[4096 + key16 * 64 + ((lgrp    ) ^ swk) * 8]);
      bf16x8 b3 = __builtin_bit_cast(bf16x8, *(const u16x8*)&KB[4096 + key16 * 64 + ((lgrp + 4) ^ swk) * 8]);
      f32x4 t1 = {}, t2 = {}, sp = {};
      t1 = MFMA16(aQ0, b0, t1); t1 = MFMA16(aQ1, b1, t1);  // q_r.k_r
      t2 = MFMA16(aQ2, b2, t2); t2 = MFMA16(aQ3, b3, t2);  // q_p.k_p
      sp = MFMA16(aQ0, b2, sp); sp = MFMA16(aQ1, b3, sp);  // q_r.k_p
      sp = MFMA16(aQ2, b0, sp); sp = MFMA16(aQ3, b1, sp);  // q_p.k_r
      #pragma unroll
      for (int r = 0; r < 4; ++r) {
        lsR[r] += __expf((t1[r] - t2[r]) * 0.125f);
        lsP[r] += __expf(sp[r] * 0.125f);
      }
    }
    __syncthreads();                 // all waves done reading KT[cur]
    if (i + 2 < 8) issue(slice * 8 + i + 2, cur);
    cur ^= 1;
  }

  #pragma unroll
  for (int r = 0; r < 4; ++r) {
    float sR = lsR[r], sP = lsP[r];
    #pragma unroll
    for (int m = 1; m < 16; m <<= 1) {
      sR += __shfl_xor(sR, m, 64);
      sP += __shfl_xor(sP, m, 64);
    }
    if (lrow == 0) {
      const size_t row = (size_t)b * SEQ + qtile * 64 + wq * 16 + lgrp * 4 + r;
      wsums[(size_t)(slice * 2 + 0) * BQ + row] = sR;
      wsums[(size_t)(slice * 2 + 1) * BQ + row] = sP;
    }
  }
}

// ---------------- Kernel 2: PV + normalized attn (full key range) ----------------
// One block = 64 q-rows x ALL 2048 keys; 512 blocks, LDS 72KB (double-buffered
// KV + P panels) -> 2 blocks/CU. Counted vmcnt(8) pipeline: next tile's loads
// stay in flight across both barriers. O complete per block -> direct store.
__global__ __launch_bounds__(256, 2)
void ck_main(const unsigned short* __restrict__ qb,
             const unsigned short* __restrict__ kv,
             const float* __restrict__ wsums, float* __restrict__ dout)
{
  __shared__ __align__(16) unsigned short KV[2][16384];   // 64KB: Kr,Kp,Vr,Vp x2
  __shared__ __align__(16) unsigned short Pr[64][32], Pp[64][32];

  const int tid  = threadIdx.x;
  const int wq   = tid >> 6, lane = tid & 63;
  const int lrow = lane & 15, lgrp = lane >> 4;

  const int hw = blockIdx.x;                       // XCD swizzle (512 = 8*64)
  const int logical = (hw & 7) * 64 + (hw >> 3);
  const int b = logical >> 5, qtile = logical & 31;

  float* outR = dout;
  float* outP = dout + MAT;
  float* attn = dout + 2 * MAT + ((size_t)b * SEQ + (size_t)qtile * 64) * SEQ;

  const int qrow = qtile * 64 + wq * 16 + lrow;
  const size_t qoff = ((size_t)b * SEQ + qrow) * DK;
  bf16x8 aQ0 = __builtin_bit_cast(bf16x8, *(const u16x8*)(qb + qoff + lgrp * 8));
  bf16x8 aQ1 = __builtin_bit_cast(bf16x8, *(const u16x8*)(qb + qoff + 32 + lgrp * 8));
  bf16x8 aQ2 = __builtin_bit_cast(bf16x8, *(const u16x8*)(qb + MAT + qoff + lgrp * 8));
  bf16x8 aQ3 = __builtin_bit_cast(bf16x8, *(const u16x8*)(qb + MAT + qoff + 32 + lgrp * 8));

  const int qloc = wq * 16 + lgrp * 4;
  float iR[4], iP[4];
  {
    const size_t base = (size_t)b * SEQ + qtile * 64 + qloc;
    #pragma unroll
    for (int r = 0; r < 4; ++r) {
      float sR = 0.f, sP = 0.f;
      #pragma unroll
      for (int z = 0; z < 4; ++z) {
        sR += wsums[(size_t)(z * 2 + 0) * BQ + base + r];
        sP += wsums[(size_t)(z * 2 + 1) * BQ + base + r];
      }
      iR[r] = 1.0f / sR;
      iP[r] = 1.0f / sP;
    }
  }

  auto issue = [&](int tile, int buf) {
    const unsigned short* src = kv + (size_t)(b * 32 + tile) * TILEU;
    #pragma unroll
    for (int c = 0; c < 8; ++c) {   // 32KB = 32 x 1KB chunks, 8 per wave
      const int ch = wq * 8 + c;
      gload16(src + ch * 512 + lane * 8, &KV[buf][ch * 512]);
    }
  };

  const u16x8 SGN = {0x8000, 0x8000, 0x8000, 0x8000, 0x8000, 0x8000, 0x8000, 0x8000};
  f32x4 accR[4] = {}, accP[4] = {};

  issue(0, 0);
  issue(1, 1);
  int cur = 0;
  for (int i = 0; i < 32; ++i) {
    const int k0 = i * 64;
    if (i < 31) { asm volatile("s_waitcnt vmcnt(8)" ::: "memory"); }  // next tile in flight
    else        { asm volatile("s_waitcnt vmcnt(0)" ::: "memory"); }
    __builtin_amdgcn_sched_barrier(0);
    __syncthreads();

    const unsigned short* KB = KV[cur];
    #pragma unroll
    for (int h = 0; h < 2; ++h) {
      #pragma unroll
      for (int t = 0; t < 2; ++t) {
        const int key16 = (h * 2 + t) * 16 + lrow;
        const int swk = lrow & 7;
        bf16x8 b0 = __builtin_bit_cast(bf16x8, *(const u16x8*)&KB[key16 * 64 + ((lgrp    ) ^ swk) * 8]);
        bf16x8 b1 = __builtin_bit_cast(bf16x8, *(const u16x8*)&KB[key16 * 64 + ((lgrp + 4) ^ swk) * 8]);
        bf16x8 b2 = __builtin_bit_cast(bf16x8, *(const u16x8*)&KB[4096 + key16 * 64 + ((lgrp    ) ^ swk) * 8]);
        bf16x8 b3 = __builtin_bit_cast(bf16x8, *(const u16x8*)&KB[4096 + key16 * 64 + ((lgrp + 4) ^ swk) * 8]);
        f32x4 t1 = {}, t2 = {}, sp = {};
        t1 = MFMA16(aQ0, b0, t1); t1 = MFMA16(aQ1, b1, t1);
        t2 = MFMA16(aQ2, b2, t2); t2 = MFMA16(aQ3, b3, t2);
        sp = MFMA16(aQ0, b2, sp); sp = MFMA16(aQ1, b3, sp);
        sp = MFMA16(aQ2, b0, sp); sp = MFMA16(aQ3, b1, sp);
        #pragma unroll
        for (int r = 0; r < 4; ++r) {
          const float er = __expf((t1[r] - t2[r]) * 0.125f) * iR[r];
          const float ep = __expf(sp[r] * 0.125f) * iP[r];
          const int row = qloc + r, col = t * 16 + lrow;
          const int pc = ((col >> 3) ^ (row & 3)) * 8 + (col & 7);
          Pr[row][pc] = bfbits(er);   // wave-private rows: no barrier
          Pp[row][pc] = bfbits(ep);
        }
      }
      { // PV: accR += Pr.Vr + (-Pp).Vp ; accP += Pr.Vp + Pp.Vr
        const int prow = wq * 16 + lrow;
        u16x8 uar = *(const u16x8*)&Pr[prow][(lgrp ^ (prow & 3)) * 8];
        u16x8 uap = *(const u16x8*)&Pp[prow][(lgrp ^ (prow & 3)) * 8];
        u16x8 uan = uap ^ SGN;
        bf16x8 apr = __builtin_bit_cast(bf16x8, uar);
        bf16x8 app = __builtin_bit_cast(bf16x8, uap);
        bf16x8 apn = __builtin_bit_cast(bf16x8, uan);
        #pragma unroll
        for (int nt = 0; nt < 4; ++nt) {
          const int d = nt * 16 + lrow;
          const int cv = ((h * 4 + lgrp) ^ (d & 7)) * 8;
          bf16x8 bvr = __builtin_bit_cast(bf16x8, *(const u16x8*)&KB[8192  + d * 64 + cv]);
          bf16x8 bvp = __builtin_bit_cast(bf16x8, *(const u16x8*)&KB[12288 + d * 64 + cv]);
          accR[nt] = MFMA16(apr, bvr, accR[nt]);
          accR[nt] = MFMA16(apn, bvp, accR[nt]);
          accP[nt] = MFMA16(apr, bvp, accP[nt]);
          accP[nt] = MFMA16(app, bvr, accP[nt]);
        }
      }
      { // attn write: full 128B lines (8 lanes x 16B per row), NT
        const int j8 = lane & 7;
        #pragma unroll
        for (int s = 0; s < 2; ++s) {
          const int arow = wq * 16 + s * 8 + (lane >> 3);
          const int pc = (((j8 >> 1) ^ (arow & 3)) * 8) + (j8 & 1) * 4;
          u16x4 ua = *(const u16x4*)&Pr[arow][pc];
          f32x4 fa;
          #pragma unroll
          for (int q = 0; q < 4; ++q)
            fa[q] = __builtin_bit_cast(float, (unsigned)ua[q] << 16);
          float* dst = attn + (size_t)arow * SEQ + k0 + h * 32 + j8 * 4;
          __builtin_nontemporal_store(fa, (f32x4*)dst);
        }
      }
    }
    __syncthreads();                 // all waves done reading KV[cur]
    if (i + 2 < 32) issue(i + 2, cur);
    cur ^= 1;
  }

  // ---- O complete per block: direct store ----
  #pragma unroll
  for (int nt = 0; nt < 4; ++nt) {
    const int d = nt * 16 + lrow;
    #pragma unroll
    for (int r = 0; r < 4; ++r) {
      const size_t o = ((size_t)b * SEQ + qtile * 64 + qloc + r) * DK + d;
      outR[o] = accR[nt][r];
      outP[o] = accP[nt][r];
    }
  }
}

extern "C" void kernel_launch(void* const* d_in, const int* in_sizes, int n_in,
                              void* d_out, int out_size, void* d_ws, size_t ws_size,
                              hipStream_t stream)
{
  const float* qr = (const float*)d_in[0];
  const float* kr = (const float*)d_in[1];
  const float* vr = (const float*)d_in[2];
  const float* qp = (const float*)d_in[3];
  const float* kp = (const float*)d_in[4];
  const float* vp = (const float*)d_in[5];
  float* out = (float*)d_out;

  // ws: [kv bf16 tiles 16MB][qb bf16 8MB][wsums 1MB]
  unsigned short* kv = (unsigned short*)d_ws;
  unsigned short* qb = (unsigned short*)((char*)d_ws + (16u << 20));
  float* wsums = (float*)((char*)d_ws + (24u << 20));

  const unsigned qblocks = (unsigned)(2 * MAT / 8 / 256);
  ck_prep<<<BATCH * 32 + qblocks, 256, 0, stream>>>(kr, kp, vr, vp, qr, qp, kv, qb);
  ck_sums<<<4 * 32 * BATCH, 256, 0, stream>>>(qb, kv, wsums);
  ck_main<<<32 * BATCH, 256, 0, stream>>>(qb, kv, wsums, out);
}